// Round 6
// baseline (5264.054 us; speedup 1.0000x reference)
//
#include <hip/hip_runtime.h>
#include <hip/hip_fp16.h>

// LightGCN propagation on MI355X — round 6: col-binned LDS-accumulator SpMM.
// N = 100000 nodes, D = 128, E = 2,000,000 edges, 3 layers.
//
// Round-5: spmm = 3x114 us, bound by L2-miss gather traffic (FETCH 302 MB vs
// 512 MB logical, 41% cache absorption). Round 6:
//   - Edges per row-bucket are sorted by column-BIN (col>>7), row kept packed
//     in the word. SpMM = one block per bucket, 128x128 fp32 acc in LDS
//     (ds_add_f32, 2-way bank aliasing = free). Resident blocks walk column
//     space in rough lockstep -> concurrent gathers cluster in a small col
//     window -> per-XCD L2 hits instead of L3 round-trips.
//   - lgcn_count takes per-(block,bucket) bases directly via one aggregated
//     global atomicAdd per bucket per block (partition order is irrelevant:
//     colsort re-orders anyway) -> serial gscan writeback eliminated.
//   - row_ptr / per-row CSR eliminated entirely.

#define DIM 128
#define RPB 128        // rows per bucket
#define RPB_SHIFT 7
#define CHUNK 8192     // edges per partition block
#define COLMASK 0x1FFFF

static inline size_t align_up(size_t v, size_t a) { return (v + a - 1) & ~(a - 1); }

__global__ void lgcn_conv(const float2* __restrict__ emb, __half2* __restrict__ x0,
                          int n2) {
    int i = blockIdx.x * blockDim.x + threadIdx.x;
    if (i < n2) x0[i] = __float22half2_rn(emb[i]);
}

// k1: per-block bucket histogram; block base within bucket via one aggregated
// global atomicAdd per (block,bucket). ghist[b][i] = block-relative base.
__global__ void __launch_bounds__(256)
lgcn_count(const int* __restrict__ rows, int* __restrict__ bcnt,
           int* __restrict__ ghist, int nedges, int nb) {
    __shared__ int h[1024];
    const int tid = threadIdx.x;
    for (int i = tid; i < nb; i += 256) h[i] = 0;
    __syncthreads();
    const int e0 = blockIdx.x * CHUNK;
    const int e1 = min(e0 + CHUNK, nedges);
    for (int e = e0 + tid; e < e1; e += 256)
        atomicAdd(&h[rows[e] >> RPB_SHIFT], 1);
    __syncthreads();
    int* g = ghist + (size_t)blockIdx.x * nb;
    for (int i = tid; i < nb; i += 256) {
        int v = h[i];
        g[i] = v ? atomicAdd(&bcnt[i], v) : 0;
    }
}

// k2: exclusive scan of the nb (<=1024) bucket totals.
__global__ void __launch_bounds__(1024)
lgcn_bscan(const int* __restrict__ bcnt, int* __restrict__ bbase, int nb) {
    __shared__ int wsum[16];
    const int tid  = threadIdx.x;
    const int lane = tid & 63;
    const int wid  = tid >> 6;
    int v = (tid < nb) ? bcnt[tid] : 0;
    int incl = v;
    #pragma unroll
    for (int off = 1; off < 64; off <<= 1) {
        int t = __shfl_up(incl, off, 64);
        if (lane >= off) incl += t;
    }
    if (lane == 63) wsum[wid] = incl;
    __syncthreads();
    if (wid == 0 && lane < 16) {
        int w = wsum[lane];
        #pragma unroll
        for (int off = 1; off < 16; off <<= 1) {
            int t = __shfl_up(w, off, 64);
            if (lane >= off) w += t;
        }
        wsum[lane] = w;
    }
    __syncthreads();
    int ex = incl - v + ((wid > 0) ? wsum[wid - 1] : 0);
    if (tid < nb) {
        bbase[tid] = ex;
        if (tid == nb - 1) bbase[nb] = ex + v;
    }
}

// k3: scatter to buckets via LDS cursors seeded with bbase + block base.
__global__ void __launch_bounds__(256)
lgcn_scat(const int* __restrict__ rows, const int* __restrict__ cols,
          const float* __restrict__ vals, const int* __restrict__ ghist,
          const int* __restrict__ bbase, int2* __restrict__ binned,
          int nedges, int nb) {
    __shared__ int lcur[1024];
    const int tid = threadIdx.x;
    const int* g  = ghist + (size_t)blockIdx.x * nb;
    for (int i = tid; i < nb; i += 256) lcur[i] = bbase[i] + g[i];
    __syncthreads();
    const int e0 = blockIdx.x * CHUNK;
    const int e1 = min(e0 + CHUNK, nedges);
    for (int e = e0 + tid; e < e1; e += 256) {
        int r   = rows[e];
        int pos = atomicAdd(&lcur[r >> RPB_SHIFT], 1);
        binned[pos] = make_int2(((r & (RPB - 1)) << 17) | cols[e],
                                __float_as_int(vals[e]));
    }
}

// k4: per bucket, re-order edges by column bin (col>>7). Row stays packed.
__global__ void __launch_bounds__(256)
lgcn_colsort(const int2* __restrict__ binned, const int* __restrict__ bbase,
             int2* __restrict__ edges, int nb) {
    __shared__ int hist[1024];
    __shared__ int cur[1024];
    __shared__ int wsum[4];
    const int b    = blockIdx.x;
    const int tid  = threadIdx.x;
    const int base = bbase[b];
    const int cnt  = bbase[b + 1] - base;
    const int lane = tid & 63;
    const int wid  = tid >> 6;

    for (int i = tid; i < 1024; i += 256) hist[i] = 0;
    __syncthreads();
    for (int i = tid; i < cnt; i += 256)
        atomicAdd(&hist[(binned[base + i].x & COLMASK) >> RPB_SHIFT], 1);
    __syncthreads();

    // block-wide exclusive scan of 1024 bins, 4 per thread
    const int i0 = tid * 4;
    int c0 = hist[i0], c1 = hist[i0 + 1], c2 = hist[i0 + 2], c3 = hist[i0 + 3];
    const int t1 = c0 + c1, t2 = t1 + c2, ts = t2 + c3;
    int incl = ts;
    #pragma unroll
    for (int off = 1; off < 64; off <<= 1) {
        int t = __shfl_up(incl, off, 64);
        if (lane >= off) incl += t;
    }
    if (lane == 63) wsum[wid] = incl;
    __syncthreads();
    int woff = 0;
    #pragma unroll
    for (int w = 0; w < 4; ++w) woff += (w < wid) ? wsum[w] : 0;
    const int ex = base + woff + incl - ts;
    cur[i0]     = ex;
    cur[i0 + 1] = ex + c0;
    cur[i0 + 2] = ex + t1;
    cur[i0 + 3] = ex + t2;
    __syncthreads();

    for (int i = tid; i < cnt; i += 256) {
        int2 p  = binned[base + i];
        int  cb = (p.x & COLMASK) >> RPB_SHIFT;
        int pos = atomicAdd(&cur[cb], 1);
        edges[pos] = p;
    }
}

// k5: SpMM, one bucket at a time per block; 128x128 fp32 acc in LDS.
// Lane j handles dims {2j, 2j+1}. Edges are col-binned -> resident blocks
// progress through column space in rough lockstep (L2-friendly).
// mode 0: xout[row] = fp16(acc_row)
// mode 1: out[row]  = (emb + x1 + xin(=x2) + acc_row) * 0.25 (fp32)
__global__ void __launch_bounds__(512)
lgcn_spmm(const int2* __restrict__ edges, const int* __restrict__ bbase,
          const __half2* __restrict__ xin, __half2* __restrict__ xout,
          const float2* __restrict__ emb, const __half2* __restrict__ x1h,
          float2* __restrict__ out, int n, int nb, int mode) {
    __shared__ float acc[RPB * DIM];  // 64 KB
    const int tid  = threadIdx.x;
    const int wid  = tid >> 6;   // 0..7
    const int lane = tid & 63;

    for (int b = blockIdx.x; b < nb; b += gridDim.x) {
        float4* accv = (float4*)acc;
        for (int i = tid; i < RPB * DIM / 4; i += 512)
            accv[i] = make_float4(0.f, 0.f, 0.f, 0.f);
        __syncthreads();

        const int beg = bbase[b];
        const int end = bbase[b + 1];
        for (int e0 = beg + wid * 4; e0 < end; e0 += 32) {
            if (e0 + 4 <= end) {
                int2 p0 = edges[e0], p1 = edges[e0 + 1];
                int2 p2 = edges[e0 + 2], p3 = edges[e0 + 3];
                float2 a0 = __half22float2(xin[(p0.x & COLMASK) * 64 + lane]);
                float2 a1 = __half22float2(xin[(p1.x & COLMASK) * 64 + lane]);
                float2 a2 = __half22float2(xin[(p2.x & COLMASK) * 64 + lane]);
                float2 a3 = __half22float2(xin[(p3.x & COLMASK) * 64 + lane]);
                float v0 = __int_as_float(p0.y), v1 = __int_as_float(p1.y);
                float v2 = __int_as_float(p2.y), v3 = __int_as_float(p3.y);
                int r0 = (p0.x >> 17) * DIM + 2 * lane;
                int r1 = (p1.x >> 17) * DIM + 2 * lane;
                int r2 = (p2.x >> 17) * DIM + 2 * lane;
                int r3 = (p3.x >> 17) * DIM + 2 * lane;
                atomicAdd(&acc[r0],     v0 * a0.x);
                atomicAdd(&acc[r0 + 1], v0 * a0.y);
                atomicAdd(&acc[r1],     v1 * a1.x);
                atomicAdd(&acc[r1 + 1], v1 * a1.y);
                atomicAdd(&acc[r2],     v2 * a2.x);
                atomicAdd(&acc[r2 + 1], v2 * a2.y);
                atomicAdd(&acc[r3],     v3 * a3.x);
                atomicAdd(&acc[r3 + 1], v3 * a3.y);
            } else {
                for (int e = e0; e < end; ++e) {
                    int2 p = edges[e];
                    float2 a = __half22float2(xin[(p.x & COLMASK) * 64 + lane]);
                    float v  = __int_as_float(p.y);
                    int r = (p.x >> 17) * DIM + 2 * lane;
                    atomicAdd(&acc[r],     v * a.x);
                    atomicAdd(&acc[r + 1], v * a.y);
                }
            }
        }
        __syncthreads();

        const int rowbase = b * RPB;
        if (mode == 0) {
            for (int j = tid; j < RPB * 64; j += 512) {
                int r = j >> 6, c = j & 63;
                int g = rowbase + r;
                if (g < n) {
                    float2 s = *(const float2*)&acc[r * DIM + 2 * c];
                    xout[g * 64 + c] = __float22half2_rn(s);
                }
            }
        } else {
            for (int j = tid; j < RPB * 64; j += 512) {
                int r = j >> 6, c = j & 63;
                int g = rowbase + r;
                if (g < n) {
                    float2 s  = *(const float2*)&acc[r * DIM + 2 * c];
                    float2 em = emb[g * 64 + c];
                    float2 b1 = __half22float2(x1h[g * 64 + c]);
                    float2 b2 = __half22float2(xin[g * 64 + c]);
                    out[g * 64 + c] = make_float2((em.x + b1.x + b2.x + s.x) * 0.25f,
                                                  (em.y + b1.y + b2.y + s.y) * 0.25f);
                }
            }
        }
        __syncthreads();  // acc reads done before next bucket's zeroing
    }
}

extern "C" void kernel_launch(void* const* d_in, const int* in_sizes, int n_in,
                              void* d_out, int out_size, void* d_ws, size_t ws_size,
                              hipStream_t stream) {
    const float* emb  = (const float*)d_in[0];
    const int*   rows = (const int*)d_in[1];
    const int*   cols = (const int*)d_in[2];
    const float* vals = (const float*)d_in[3];

    const int  n_nodes = in_sizes[0] / DIM;            // 100000
    const int  nedges  = in_sizes[1];                  // 2000000
    const long nd      = (long)n_nodes * DIM;          // 12.8M
    const int  nb      = (n_nodes + RPB - 1) / RPB;    // 782
    const int  nblk    = (nedges + CHUNK - 1) / CHUNK; // 245

    char* ws = (char*)d_ws;
    size_t off = 0;
    __half2* bufA = (__half2*)(ws + off); off = align_up(off + nd * 2, 256);   // x0, then x2
    __half2* bufB = (__half2*)(ws + off); off = align_up(off + nd * 2, 256);   // x1
    int2* binned  = (int2*)(ws + off);    off = align_up(off + (size_t)nedges * 8, 256);
    int2* edges   = (int2*)(ws + off);    off = align_up(off + (size_t)nedges * 8, 256);
    int* ghist    = (int*)(ws + off);     off = align_up(off + (size_t)nblk * nb * 4, 256);
    int* bcnt     = (int*)(ws + off);     off = align_up(off + (size_t)(nb + 1) * 4, 256);
    int* bbase    = (int*)(ws + off);     off = align_up(off + (size_t)(nb + 1) * 4, 256);
    float2* out   = (float2*)d_out;

    const int BS = 256;
    const int n2     = (int)(nd / 2);
    const int grid_c = (n2 + BS - 1) / BS;

    // emb -> fp16 x0
    lgcn_conv<<<grid_c, BS, 0, stream>>>((const float2*)emb, bufA, n2);

    // Partition by row-bucket, then col-bin within bucket
    hipMemsetAsync(bcnt, 0, (size_t)nb * sizeof(int), stream);
    lgcn_count<<<nblk, BS, 0, stream>>>(rows, bcnt, ghist, nedges, nb);
    lgcn_bscan<<<1, 1024, 0, stream>>>(bcnt, bbase, nb);
    lgcn_scat<<<nblk, BS, 0, stream>>>(rows, cols, vals, ghist, bbase, binned,
                                       nedges, nb);
    lgcn_colsort<<<nb, BS, 0, stream>>>(binned, bbase, edges, nb);

    // 3 SpMM layers: x1 = A x0, x2 = A x1, out = (emb + x1 + x2 + A x2)/4
    lgcn_spmm<<<512, 512, 0, stream>>>(edges, bbase, bufA, bufB,
                                       nullptr, nullptr, nullptr, n_nodes, nb, 0);
    lgcn_spmm<<<512, 512, 0, stream>>>(edges, bbase, bufB, bufA,
                                       nullptr, nullptr, nullptr, n_nodes, nb, 0);
    lgcn_spmm<<<512, 512, 0, stream>>>(edges, bbase, bufA, nullptr,
                                       (const float2*)emb, bufB, out, n_nodes, nb, 1);
}

// Round 8
// 594.850 us; speedup vs baseline: 8.8494x; 8.8494x over previous
//
#include <hip/hip_runtime.h>
#include <hip/hip_fp16.h>

// LightGCN propagation on MI355X — round 8.
// N = 100000 nodes, D = 128, E = 2,000,000 edges, 3 layers.
//
// Round-7 FAILED under graph replay (first call correct, replays diverged
// 0.62 + 4x slower) — the only r7-unique code was the spmm clamped-batch /
// readfirstlane loop. Reverted: spmm and the whole build pipeline are
// r5-verbatim (validated under replay at 593 us).
//
// Single change this round: lgcn_csr's counting-sort key is now
// (row & 127) * 8 | (col >> 14)  — 1024 bins instead of 128. Edges within a
// row come out column-sorted at 16K-col granularity (~4.2 MB fp16 segment ~=
// one XCD L2). Waves walk rows in sorted-col order and have similar degrees,
// so concurrent gathers cluster in an L2-sized column window (r6's locality
// idea without its fatal LDS atomics). row_ptr = scan value at bin row*8.

#define DIM 128
#define RPB 128        // rows per bucket
#define RPB_SHIFT 7
#define CHUNK 8192     // edges per partition block
#define COLMASK 0x1FFFF

static inline size_t align_up(size_t v, size_t a) { return (v + a - 1) & ~(a - 1); }

__global__ void lgcn_conv(const float2* __restrict__ emb, __half2* __restrict__ x0,
                          int n2) {
    int i = blockIdx.x * blockDim.x + threadIdx.x;
    if (i < n2) x0[i] = __float22half2_rn(emb[i]);
}

// k1: per-block bucket histogram -> ghist[b][i] (coalesced).
__global__ void __launch_bounds__(256)
lgcn_count(const int* __restrict__ rows, int* __restrict__ ghist,
           int nedges, int nb) {
    __shared__ int h[1024];
    const int tid = threadIdx.x;
    for (int i = tid; i < nb; i += 256) h[i] = 0;
    __syncthreads();
    const int e0 = blockIdx.x * CHUNK;
    const int e1 = min(e0 + CHUNK, nedges);
    for (int e = e0 + tid; e < e1; e += 256)
        atomicAdd(&h[rows[e] >> RPB_SHIFT], 1);
    __syncthreads();
    int* g = ghist + (size_t)blockIdx.x * nb;
    for (int i = tid; i < nb; i += 256) g[i] = h[i];
}

// k2: bucket totals -> exclusive bases; ghist[b][i] -> absolute base for
// block b's run within bucket i. Single 1024-thread block (nb <= 1024).
__global__ void __launch_bounds__(1024)
lgcn_gscan(int* __restrict__ ghist, int* __restrict__ bbase,
           int* __restrict__ row_ptr, int nblk, int nb, int n) {
    __shared__ int wsum[16];
    const int tid  = threadIdx.x;
    const int lane = tid & 63;
    const int wid  = tid >> 6;
    int total = 0;
    if (tid < nb)
        for (int b = 0; b < nblk; ++b) total += ghist[(size_t)b * nb + tid];
    int incl = total;
    #pragma unroll
    for (int off = 1; off < 64; off <<= 1) {
        int t = __shfl_up(incl, off, 64);
        if (lane >= off) incl += t;
    }
    if (lane == 63) wsum[wid] = incl;
    __syncthreads();
    if (wid == 0 && lane < 16) {
        int w = wsum[lane];
        #pragma unroll
        for (int off = 1; off < 16; off <<= 1) {
            int t = __shfl_up(w, off, 64);
            if (lane >= off) w += t;
        }
        wsum[lane] = w;
    }
    __syncthreads();
    int ex = incl - total + ((wid > 0) ? wsum[wid - 1] : 0);
    if (tid < nb) {
        bbase[tid] = ex;
        if (tid == nb - 1) {
            bbase[nb]  = ex + total;
            row_ptr[n] = ex + total;
        }
        int run = ex;
        for (int b = 0; b < nblk; ++b) {
            int t = ghist[(size_t)b * nb + tid];
            ghist[(size_t)b * nb + tid] = run;
            run += t;
        }
    }
}

// k3: scatter into buckets via LDS cursors (no global atomics).
__global__ void __launch_bounds__(256)
lgcn_scat(const int* __restrict__ rows, const int* __restrict__ cols,
          const float* __restrict__ vals, const int* __restrict__ ghist,
          int2* __restrict__ binned, int nedges, int nb) {
    __shared__ int lcur[1024];
    const int tid = threadIdx.x;
    const int* g  = ghist + (size_t)blockIdx.x * nb;
    for (int i = tid; i < nb; i += 256) lcur[i] = g[i];
    __syncthreads();
    const int e0 = blockIdx.x * CHUNK;
    const int e1 = min(e0 + CHUNK, nedges);
    for (int e = e0 + tid; e < e1; e += 256) {
        int r   = rows[e];
        int pos = atomicAdd(&lcur[r >> RPB_SHIFT], 1);
        binned[pos] = make_int2(((r & (RPB - 1)) << 17) | cols[e],
                                __float_as_int(vals[e]));
    }
}

// k4: per-bucket counting sort by key = (row&127)*8 | (col>>14).
// -> edges grouped by row (row_ptr contiguous) AND col-sorted within row at
// 16K granularity. row_ptr[row] = scan value at bin row*8.
__global__ void __launch_bounds__(256)
lgcn_csr(const int2* __restrict__ binned, const int* __restrict__ bbase,
         int* __restrict__ row_ptr, int2* __restrict__ edges, int n) {
    __shared__ int hist[1024];
    __shared__ int cur[1024];
    __shared__ int wsum[4];
    const int b    = blockIdx.x;
    const int tid  = threadIdx.x;
    const int base = bbase[b];
    const int cnt  = bbase[b + 1] - base;
    const int lane = tid & 63;
    const int wid  = tid >> 6;

    for (int i = tid; i < 1024; i += 256) hist[i] = 0;
    __syncthreads();
    for (int i = tid; i < cnt; i += 256) {
        int px  = binned[base + i].x;
        int key = ((px >> 17) << 3) | ((px & COLMASK) >> 14);
        atomicAdd(&hist[key], 1);
    }
    __syncthreads();

    // block-wide exclusive scan of 1024 bins, 4 per thread
    const int i0 = tid * 4;
    int c0 = hist[i0], c1 = hist[i0 + 1], c2 = hist[i0 + 2], c3 = hist[i0 + 3];
    const int t1 = c0 + c1, t2 = t1 + c2, ts = t2 + c3;
    int incl = ts;
    #pragma unroll
    for (int off = 1; off < 64; off <<= 1) {
        int t = __shfl_up(incl, off, 64);
        if (lane >= off) incl += t;
    }
    if (lane == 63) wsum[wid] = incl;
    __syncthreads();
    int woff = 0;
    #pragma unroll
    for (int w = 0; w < 4; ++w) woff += (w < wid) ? wsum[w] : 0;
    const int ex = woff + incl - ts;
    cur[i0]     = ex;
    cur[i0 + 1] = ex + c0;
    cur[i0 + 2] = ex + t1;
    cur[i0 + 3] = ex + t2;
    __syncthreads();

    if (tid < RPB) {
        int g = b * RPB + tid;
        if (g < n) row_ptr[g] = base + cur[tid * 8];
    }
    __syncthreads();  // row_ptr reads of cur done before scatter mutates cur

    for (int i = tid; i < cnt; i += 256) {
        int2 p  = binned[base + i];
        int key = ((p.x >> 17) << 3) | ((p.x & COLMASK) >> 14);
        int pos = atomicAdd(&cur[key], 1);
        edges[base + pos] = make_int2(p.x & COLMASK, p.y);
    }
}

// k5: SpMM (r5-verbatim). One wave per row; lane j holds dims [2j, 2j+1].
// mode 0: xout[row] = fp16(s)
// mode 1: out[row]  = (emb[row] + x1[row] + xin[row](=x2) + s) * 0.25  (fp32)
__global__ void __launch_bounds__(256)
lgcn_spmm(const int* __restrict__ row_ptr, const int2* __restrict__ edges,
          const __half2* __restrict__ xin, __half2* __restrict__ xout,
          const float2* __restrict__ emb, const __half2* __restrict__ x1h,
          float2* __restrict__ out, int n, int mode) {
    const int wave = blockIdx.x * 4 + (threadIdx.x >> 6);
    const int lane = threadIdx.x & 63;
    if (wave >= n) return;
    const int beg = row_ptr[wave];
    const int end = row_ptr[wave + 1];

    float sx = 0.f, sy = 0.f;
    int e = beg;
    for (; e + 8 <= end; e += 8) {
        long long q[8];
        #pragma unroll
        for (int k = 0; k < 8; ++k)
            q[k] = __builtin_nontemporal_load((const long long*)(edges + e + k));
        #pragma unroll
        for (int k = 0; k < 8; ++k) {
            int   c = (int)(q[k] & 0xFFFFFFFFll);
            float v = __int_as_float((int)(q[k] >> 32));
            float2 a = __half22float2(xin[c * 64 + lane]);
            sx = fmaf(v, a.x, sx); sy = fmaf(v, a.y, sy);
        }
    }
    for (; e < end; ++e) {
        long long q = __builtin_nontemporal_load((const long long*)(edges + e));
        int   c = (int)(q & 0xFFFFFFFFll);
        float v = __int_as_float((int)(q >> 32));
        float2 a = __half22float2(xin[c * 64 + lane]);
        sx = fmaf(v, a.x, sx); sy = fmaf(v, a.y, sy);
    }

    const int o = wave * 64 + lane;
    if (mode == 0) {
        xout[o] = __float22half2_rn(make_float2(sx, sy));
    } else {
        float2 em = emb[o];
        float2 b1 = __half22float2(x1h[o]);
        float2 b2 = __half22float2(xin[o]);
        out[o] = make_float2((em.x + b1.x + b2.x + sx) * 0.25f,
                             (em.y + b1.y + b2.y + sy) * 0.25f);
    }
}

extern "C" void kernel_launch(void* const* d_in, const int* in_sizes, int n_in,
                              void* d_out, int out_size, void* d_ws, size_t ws_size,
                              hipStream_t stream) {
    const float* emb  = (const float*)d_in[0];
    const int*   rows = (const int*)d_in[1];
    const int*   cols = (const int*)d_in[2];
    const float* vals = (const float*)d_in[3];

    const int  n_nodes = in_sizes[0] / DIM;            // 100000
    const int  nedges  = in_sizes[1];                  // 2000000
    const long nd      = (long)n_nodes * DIM;          // 12.8M
    const int  nb      = (n_nodes + RPB - 1) / RPB;    // 782
    const int  nblk    = (nedges + CHUNK - 1) / CHUNK; // 245

    char* ws = (char*)d_ws;
    size_t off = 0;
    __half2* bufA = (__half2*)(ws + off); off = align_up(off + nd * 2, 256);   // x0, then x2
    __half2* bufB = (__half2*)(ws + off); off = align_up(off + nd * 2, 256);   // x1
    int2* binned  = (int2*)(ws + off);    off = align_up(off + (size_t)nedges * 8, 256);
    int2* edges   = (int2*)(ws + off);    off = align_up(off + (size_t)nedges * 8, 256);
    int* ghist    = (int*)(ws + off);     off = align_up(off + (size_t)nblk * nb * 4, 256);
    int* bbase    = (int*)(ws + off);     off = align_up(off + (size_t)(nb + 1) * 4, 256);
    int* row_ptr  = (int*)(ws + off);     off = align_up(off + (size_t)(n_nodes + 1) * 4, 256);
    float2* out   = (float2*)d_out;

    const int BS = 256;
    const int n2     = (int)(nd / 2);
    const int grid_c = (n2 + BS - 1) / BS;
    const int grid_s = (n_nodes + 3) / 4;   // 4 rows (waves) per block

    // emb -> fp16 x0 (independent of CSR build)
    lgcn_conv<<<grid_c, BS, 0, stream>>>((const float2*)emb, bufA, n2);

    // Block-aggregated partition + per-bucket (row, colbin) counting sort
    lgcn_count<<<nblk, BS, 0, stream>>>(rows, ghist, nedges, nb);
    lgcn_gscan<<<1, 1024, 0, stream>>>(ghist, bbase, row_ptr, nblk, nb, n_nodes);
    lgcn_scat<<<nblk, BS, 0, stream>>>(rows, cols, vals, ghist, binned, nedges, nb);
    lgcn_csr<<<nb, BS, 0, stream>>>(binned, bbase, row_ptr, edges, n_nodes);

    // 3 SpMM layers: x1 = A x0, x2 = A x1, out = (emb + x1 + x2 + A x2)/4
    lgcn_spmm<<<grid_s, BS, 0, stream>>>(row_ptr, edges, bufA, bufB,
                                         nullptr, nullptr, nullptr, n_nodes, 0);
    lgcn_spmm<<<grid_s, BS, 0, stream>>>(row_ptr, edges, bufB, bufA,
                                         nullptr, nullptr, nullptr, n_nodes, 0);
    lgcn_spmm<<<grid_s, BS, 0, stream>>>(row_ptr, edges, bufA, nullptr,
                                         (const float2*)emb, bufB, out, n_nodes, 1);
}